// Round 18
// baseline (362.576 us; speedup 1.0000x reference)
//
#include <hip/hip_runtime.h>

// Problem: B,C,H,W = 16,256,32,32; K=16384. N = 16384 rows.
// R28: R17 post-mortem: K-split-8 regressed (160us) -- occupancy pinned ~3.5
//      blocks/CU regardless of LDS/grid (3rd failed TLP lever), and doubled
//      A-staging. Reverting to R15's proven K-split-4 shell (254.7us best).
//      k2 stall audit: issue ~1000 cyc/ch vs wall ~6000 -> 6x stall-bound;
//      the A ds_read->MFMA chain (16x ~120cyc LDS latency per ch) is the
//      largest removable latency, and A IS INVARIANT ACROSS ALL 16 ch: each
//      lane consumes the same 16 fragments (S x rt) = 256B = 64 VGPR.
//      Change: preload A to registers once (16 prologue ds_reads); steady-state
//      K-loop touches NO LDS -- 4 B-loads + 16 MFMA per step, B 2-deep.
//      lb(256,2) gives the allocator room (~190 VGPR live; R16's lesson
//      inverted). Occupancy ~2 blocks/CU -- trading TLP that measurably
//      wasn't helping for a deleted dependence chain.
//      prep / k3 / k5 / thresholds byte-identical to R15.
#define KCODES 16384
#define NPOS   16384
#define KQUART 4096
#define ROWS   64
#define CAPH   80      // per-quarter cap (R15-proven)
#define M_INT  3600    // int-space margin = 7.2 x pairwise sigma (~500)
#define SX     21.166666f        // 127/6
#define SW     2080768.0f        // 16384*127

// ws float offsets (within the proven 52.7MB footprint)
#define OFF_XT    0           // [N][256] fp32 packed x
#define OFF_XQ8   4194304     // i8 plane xq [N][256] linear
#define OFF_PART  6291456     // [4096][2] k3 per-wave {mask,err} partials
#define OFF_WHP8  8388608     // i8 plane wq, SWIZZLED [qt][S][w][ct][nn][64B]
#define OFF_CAND  9437184     // u16 [N][4][CAPH=80] candidate codes
#define OFF_WN    12582912    // [K]  |w|^2 (np-pairwise exact)
#define OFF_NS1   12599296    // [N] -|f|^2
#define OFF_IDX   12615680    // [N] final argmax (int)
#define OFF_CCNT  12632064    // int [N][4] candidate counts
#define OFF_QMAX  12697600    // fp32 [N][4] per-quarter int-acc max

#define OUT_LOSS  4194304
#define OUT_IND   4194305

#define AS1 __attribute__((address_space(1)))
#define AS3 __attribute__((address_space(3)))

typedef int  i32x4 __attribute__((ext_vector_type(4)));

// ---------- K_prep: x-path (transpose + xt + xq8 + ns1) / w-path (wn + wq8) ----
// (frozen from R15)
__global__ void k_prep(const float* __restrict__ x, float* __restrict__ xt,
                       signed char* __restrict__ xq8, float* __restrict__ ns1,
                       const float4* __restrict__ w4, float* __restrict__ wn,
                       signed char* __restrict__ wq8)
{
    __shared__ __align__(16) float smem[32 * 257];
    __shared__ float t[32][33];
    const int tid = threadIdx.x;

    if (blockIdx.x < 512) {
        const int r0 = blockIdx.x * 32;
        const int b = r0 >> 10, p0 = r0 & 1023;
        const int tx = tid & 31, ty = tid >> 5;      // 32 x 8
#pragma unroll
        for (int ci = 0; ci < 8; ++ci) {
#pragma unroll
            for (int i = 0; i < 4; ++i) {
                const int cl = ty + i * 8;
                t[cl][tx] = x[(b * 256 + ci * 32 + cl) * 1024 + p0 + tx];
            }
            __syncthreads();
#pragma unroll
            for (int i = 0; i < 4; ++i) {
                const int pl = ty + i * 8;
                smem[pl * 257 + ci * 32 + tx] = t[tx][pl];
            }
            __syncthreads();
        }
#pragma unroll
        for (int i = 0; i < 8; ++i) {
            const int row = (tid >> 6) + i * 4, c4 = tid & 63;
            const float* rp = &smem[row * 257 + c4 * 4];
            float4 v;
            v.x = rp[0]; v.y = rp[1]; v.z = rp[2]; v.w = rp[3];
            ((float4*)(xt + (r0 + row) * 256))[c4] = v;
            char4 qv;
            qv.x = (signed char)min(127, max(-127, __float2int_rn(v.x * SX)));
            qv.y = (signed char)min(127, max(-127, __float2int_rn(v.y * SX)));
            qv.z = (signed char)min(127, max(-127, __float2int_rn(v.z * SX)));
            qv.w = (signed char)min(127, max(-127, __float2int_rn(v.w * SX)));
            *(char4*)(xq8 + (r0 + row) * 256 + c4 * 4) = qv;
        }
        __syncthreads();
        const int rl = tid >> 3, j = tid & 7;
        const float* qp = &smem[rl * 257];
        float h[2];
#pragma unroll
        for (int half = 0; half < 2; ++half) {
            const float* p = qp + half * 128;
            float xx = p[j];
            float r = __fmul_rn(xx, xx);
#pragma unroll
            for (int i = 1; i < 16; ++i) {
                float y = p[8 * i + j];
                r = __fadd_rn(r, __fmul_rn(y, y));
            }
            float tt = __fadd_rn(r, __shfl_xor(r, 1));
            tt = __fadd_rn(tt, __shfl_xor(tt, 2));
            tt = __fadd_rn(tt, __shfl_xor(tt, 4));
            h[half] = tt;
        }
        if (j == 0) ns1[r0 + rl] = -__fadd_rn(h[0], h[1]);
    } else {
        float4* rows = (float4*)smem;
        const int r0 = (blockIdx.x - 512) * 32;
#pragma unroll
        for (int i = 0; i < 8; ++i) {
            const int F = r0 * 64 + tid + 256 * i;
            const float4 v = w4[F];
            rows[tid + 256 * i] = v;
            char4 qv;
            qv.x = (signed char)min(127, max(-127, __float2int_rn(v.x * SW)));
            qv.y = (signed char)min(127, max(-127, __float2int_rn(v.y * SW)));
            qv.z = (signed char)min(127, max(-127, __float2int_rn(v.z * SW)));
            qv.w = (signed char)min(127, max(-127, __float2int_rn(v.w * SW)));
            const int row = F >> 6, c4 = F & 63, c = c4 * 4;
            const int qt = row >> 12, kk = row & 4095;
            const int chi = kk >> 8, rem = kk & 255;
            const int wq_ = rem >> 6, ct = (rem >> 4) & 3, n4 = rem & 15;
            const int sidx = qt * 1048576 + (chi * 4 + (c >> 6)) * 16384
                           + wq_ * 4096 + ct * 1024 + n4 * 64 + (c & 63);
            *(char4*)(wq8 + sidx) = qv;
        }
        __syncthreads();
        const int rl = tid >> 3, j = tid & 7;
        const float* qp = (const float*)&rows[rl * 64];
        float h[2];
#pragma unroll
        for (int half = 0; half < 2; ++half) {
            const float* p = qp + half * 128;
            float xx = p[j];
            float r = __fmul_rn(xx, xx);
#pragma unroll
            for (int i = 1; i < 16; ++i) {
                float y = p[8 * i + j];
                r = __fadd_rn(r, __fmul_rn(y, y));
            }
            float tt = __fadd_rn(r, __shfl_xor(r, 1));
            tt = __fadd_rn(tt, __shfl_xor(tt, 2));
            tt = __fadd_rn(tt, __shfl_xor(tt, 4));
            h[half] = tt;
        }
        if (j == 0) wn[r0 + rl] = __fadd_rn(h[0], h[1]);
    }
}

// ---------- K2: 64-row x K-quarter, A-IN-REGISTERS i8 MFMA, int threshold ------
// Block = (rowGroup = bid>>2) x (qt = bid&3). 1024 blocks. A (16KB/block) is
// staged to LDS once, then the wave's 16 invariant fragments (256B/lane) are
// preloaded to 64 VGPRs -- the 16-ch K-loop does NO LDS reads.
__global__ __launch_bounds__(256, 2) void k2_mfma(
    const signed char* __restrict__ xq8, const signed char* __restrict__ wq8,
    unsigned short* __restrict__ candk, int* __restrict__ candc,
    float* __restrict__ qmax)
{
    __shared__ __align__(16) signed char As[16384];   // 16KB: slot16 = g*64 + row
    __shared__ int rowmaxI[ROWS];
    __shared__ int ccnt[ROWS];
    __shared__ unsigned short ck[ROWS][CAPH];         // 10 KB

    const int tid  = threadIdx.x;
    const int lane = tid & 63;
    const int w    = tid >> 6;
    const int q    = lane >> 4;
    const int nn   = lane & 15;
    const int qt   = blockIdx.x & 3;
    const int rowBase = (blockIdx.x >> 2) * ROWS;
    const signed char* wq8Q = wq8 + qt * 1048576;

#pragma unroll
    for (int i = 0; i < 4; ++i) {
        const int slot = i * 256 + tid;
        const int g = slot >> 6, row = slot & 63;
        const signed char* src = xq8 + (rowBase + row) * 256 + g * 16;
        __builtin_amdgcn_global_load_lds((const AS1 void*)src,
                                         (AS3 void*)((char*)&As[0] + slot * 16), 16, 0, 0);
    }
    if (tid < ROWS) { rowmaxI[tid] = (int)0x80000000; ccnt[tid] = 0; }

    const signed char* bptr = wq8Q + (w * 4096 + nn * 64 + q * 16);

    __syncthreads();           // As staged

    // preload the wave's 16 invariant A fragments (S x rt) into registers
    i32x4 aF[4][4];
#pragma unroll
    for (int S = 0; S < 4; ++S)
#pragma unroll
        for (int rt = 0; rt < 4; ++rt)
            aF[S][rt] = *(const i32x4*)&As[(((S * 4 + q) * 64) + rt * 16 + nn) * 16];

    i32x4 b0[4], b1[4];
#pragma unroll
    for (int ct = 0; ct < 4; ++ct)
        b0[ct] = *(const i32x4*)(bptr + ct * 1024);
    const signed char* nps = bptr + 16384;

    for (int ch = 0; ch < 16; ++ch) {
        const int kb = ch * 256;
        i32x4 acc[4][4];
#pragma unroll
        for (int rt = 0; rt < 4; ++rt)
#pragma unroll
            for (int ct = 0; ct < 4; ++ct) acc[rt][ct] = (i32x4){0, 0, 0, 0};

#pragma unroll
        for (int cs2 = 0; cs2 < 2; ++cs2) {
            // EVEN step S=2*cs2: prefetch next step's B into b1, compute from b0.
            // (one-past-end prefetch lands in the candk region: valid, unused)
#pragma unroll
            for (int ct = 0; ct < 4; ++ct)
                b1[ct] = *(const i32x4*)(nps + ct * 1024);
            nps += 16384;
#pragma unroll
            for (int rt = 0; rt < 4; ++rt)
#pragma unroll
                for (int ct = 0; ct < 4; ++ct)
                    acc[rt][ct] = __builtin_amdgcn_mfma_i32_16x16x64_i8(
                        aF[2 * cs2][rt], b0[ct], acc[rt][ct], 0, 0, 0);
            // ODD step S=2*cs2+1: prefetch into b0, compute from b1.
#pragma unroll
            for (int ct = 0; ct < 4; ++ct)
                b0[ct] = *(const i32x4*)(nps + ct * 1024);
            nps += 16384;
#pragma unroll
            for (int rt = 0; rt < 4; ++rt)
#pragma unroll
                for (int ct = 0; ct < 4; ++ct)
                    acc[rt][ct] = __builtin_amdgcn_mfma_i32_16x16x64_i8(
                        aF[2 * cs2 + 1][rt], b1[ct], acc[rt][ct], 0, 0, 0);
        }

        // ---- fold on int acc: max -> atomicMax -> barrier -> collect ----
#pragma unroll
        for (int rt = 0; rt < 4; ++rt)
#pragma unroll
            for (int rg = 0; rg < 4; ++rg) {
                int m = max(max(acc[rt][0][rg], acc[rt][1][rg]),
                            max(acc[rt][2][rg], acc[rt][3][rg]));
                m = max(m, __shfl_xor(m, 1, 64));
                m = max(m, __shfl_xor(m, 2, 64));
                m = max(m, __shfl_xor(m, 4, 64));
                m = max(m, __shfl_xor(m, 8, 64));
                if (nn == 0)
                    atomicMax(&rowmaxI[rt * 16 + q * 4 + rg], m);
            }
        __syncthreads();       // rowmax merged across waves (tight threshold)
#pragma unroll
        for (int rt = 0; rt < 4; ++rt)
#pragma unroll
            for (int rg = 0; rg < 4; ++rg) {
                const int row = rt * 16 + q * 4 + rg;
                const int th = rowmaxI[row] - M_INT;
#pragma unroll
                for (int ct = 0; ct < 4; ++ct)
                    if (acc[rt][ct][rg] >= th) {
                        const int pos = atomicAdd(&ccnt[row], 1);
                        if (pos < CAPH)
                            ck[row][pos] = (unsigned short)(qt * KQUART + kb + w * 64 + ct * 16 + nn);
                    }
            }
        // no trailing barrier: stale rowmax only loosens; M_INT covers the argmax.
    }
    __syncthreads();
    if (tid < ROWS) {
        candc[(rowBase + tid) * 4 + qt] = ccnt[tid];
        qmax[(rowBase + tid) * 4 + qt] = (float)rowmaxI[tid];  // |int| < 2^24: exact
    }
#pragma unroll
    for (int i = 0; i < 20; ++i) {
        const int e = i * 256 + tid;    // 5120 entries = 64 rows x CAPH(80)
        const int row = e / CAPH, pos = e - row * CAPH;
        candk[((rowBase + row) * 4 + qt) * CAPH + pos] = ck[row][pos];
    }
}

// ---------- K3: exact fp32 rescore, quarter-skip, 2-cand ILP, fused loss -------
// (frozen from R15)
__global__ __launch_bounds__(256) void k3_rescore(
    const float* __restrict__ xt, const float* __restrict__ weight,
    const float* __restrict__ wn, const float* __restrict__ ns1,
    const float* __restrict__ qmax,
    const unsigned short* __restrict__ candk, const int* __restrict__ candc,
    const float* __restrict__ mask,
    int* __restrict__ idx, float* __restrict__ out, float* __restrict__ part)
{
    const int w = threadIdx.x >> 6, lane = threadIdx.x & 63;
    const int waveId = blockIdx.x * 4 + w;        // 0..4095
    float mm = 0.f, merr = 0.f;
#pragma unroll
    for (int rr = 0; rr < 4; ++rr) {
        const int n = waveId * 4 + rr;
        const float4 xv = ((const float4*)(xt + n * 256))[lane];
        const float nsv = ns1[n];
        const float4 qm = ((const float4*)(qmax + n * 4))[0];
        const float qth = fmaxf(fmaxf(qm.x, qm.y), fmaxf(qm.z, qm.w)) - (float)M_INT;
        float bestd = -3.0e38f; int bestk = 0x7fffffff;
#pragma unroll
        for (int qt = 0; qt < 4; ++qt) {
            const float qv = (qt == 0) ? qm.x : (qt == 1) ? qm.y : (qt == 2) ? qm.z : qm.w;
            if (qv < qth) continue;               // quarter can't hold the argmax
            const int cnt = candc[n * 4 + qt];
            const int base = (n * 4 + qt) * CAPH;
            if (cnt <= CAPH) {
                int i = 0;
                for (; i + 1 < cnt; i += 2) {     // 2-cand ILP; compare order = index order
                    const int ka = candk[base + i], kb = candk[base + i + 1];
                    const float4 wa = ((const float4*)(weight + ka * 256))[lane];
                    const float4 wb = ((const float4*)(weight + kb * 256))[lane];
                    float pa = __fmul_rn(xv.x, wa.x);
                    float pb = __fmul_rn(xv.x, wb.x);
                    pa = __builtin_fmaf(xv.y, wa.y, pa);
                    pb = __builtin_fmaf(xv.y, wb.y, pb);
                    pa = __builtin_fmaf(xv.z, wa.z, pa);
                    pb = __builtin_fmaf(xv.z, wb.z, pb);
                    pa = __builtin_fmaf(xv.w, wa.w, pa);
                    pb = __builtin_fmaf(xv.w, wb.w, pb);
#pragma unroll
                    for (int off = 1; off < 64; off <<= 1) {
                        pa += __shfl_xor(pa, off, 64);
                        pb += __shfl_xor(pb, off, 64);
                    }
                    const float da = __fadd_rn(__fadd_rn(nsv, -wn[ka]), __fmul_rn(2.0f, pa));
                    const float db = __fadd_rn(__fadd_rn(nsv, -wn[kb]), __fmul_rn(2.0f, pb));
                    if (da > bestd || (da == bestd && ka < bestk)) { bestd = da; bestk = ka; }
                    if (db > bestd || (db == bestd && kb < bestk)) { bestd = db; bestk = kb; }
                }
                if (i < cnt) {
                    const int k = candk[base + i];
                    const float4 wv = ((const float4*)(weight + k * 256))[lane];
                    float p = __fmul_rn(xv.x, wv.x);
                    p = __builtin_fmaf(xv.y, wv.y, p);
                    p = __builtin_fmaf(xv.z, wv.z, p);
                    p = __builtin_fmaf(xv.w, wv.w, p);
#pragma unroll
                    for (int off = 1; off < 64; off <<= 1) p += __shfl_xor(p, off, 64);
                    const float dd = __fadd_rn(__fadd_rn(nsv, -wn[k]), __fmul_rn(2.0f, p));
                    if (dd > bestd || (dd == bestd && k < bestk)) { bestd = dd; bestk = k; }
                }
            } else {          // overflow fallback: exact scan of this quarter
                for (int k = qt * KQUART; k < (qt + 1) * KQUART; ++k) {
                    const float4 wv = ((const float4*)(weight + k * 256))[lane];
                    float p = __fmul_rn(xv.x, wv.x);
                    p = __builtin_fmaf(xv.y, wv.y, p);
                    p = __builtin_fmaf(xv.z, wv.z, p);
                    p = __builtin_fmaf(xv.w, wv.w, p);
#pragma unroll
                    for (int off = 1; off < 64; off <<= 1) p += __shfl_xor(p, off, 64);
                    const float dd = __fadd_rn(__fadd_rn(nsv, -wn[k]), __fmul_rn(2.0f, p));
                    if (dd > bestd || (dd == bestd && k < bestk)) { bestd = dd; bestk = k; }
                }
            }
        }
        const int bk = (bestk <= (KCODES - 1)) ? bestk : 0;   // fault guard
        if (lane == 0) { idx[n] = bk; out[OUT_IND + n] = (float)bk; }
        const float4 wv = ((const float4*)(weight + bk * 256))[lane];
        float ex = wv.x - xv.x, ey = wv.y - xv.y, ez = wv.z - xv.z, ew = wv.w - xv.w;
        float s = ex * ex + ey * ey + ez * ez + ew * ew;
#pragma unroll
        for (int off = 1; off < 64; off <<= 1) s += __shfl_xor(s, off, 64);
        const float mval = mask[n];
        mm += mval; merr += mval * s;
    }
    if (lane == 0) { part[waveId * 2 + 0] = mm; part[waveId * 2 + 1] = merr; }
}

// ---------- K5: gather + transpose store; block (0,0,0) also finalizes loss ----
// (frozen from R15)
__global__ void k5_out(const float* __restrict__ weight, const int* __restrict__ idx,
                       const float* __restrict__ part, float* __restrict__ out)
{
    __shared__ float t[32][33];
    const int p0 = blockIdx.x * 32, c0 = blockIdx.y * 32, b = blockIdx.z;
    const int tx = threadIdx.x, ty = threadIdx.y;
#pragma unroll
    for (int i = 0; i < 4; ++i) {
        const int pl = ty + i * 8;
        const int n = b * 1024 + p0 + pl;
        t[tx][pl] = weight[idx[n] * 256 + c0 + tx];       // coalesced 128B per row
    }
    __syncthreads();
#pragma unroll
    for (int i = 0; i < 4; ++i) {
        const int cl = ty + i * 8;
        out[(b * 256 + c0 + cl) * 1024 + p0 + tx] = t[cl][tx];   // coalesced in tx
    }
    if (blockIdx.x == 0 && blockIdx.y == 0 && blockIdx.z == 0) {
        __shared__ double red[4][2];
        const int lin = ty * 32 + tx;     // 0..255
        double m = 0.0, s = 0.0;
        for (int i = lin; i < 4096; i += 256) {
            m += (double)part[i * 2 + 0];
            s += (double)part[i * 2 + 1];
        }
        const int lane = lin & 63, wv = lin >> 6;
        for (int o = 32; o > 0; o >>= 1) {
            m += __shfl_down(m, o, 64);
            s += __shfl_down(s, o, 64);
        }
        if (lane == 0) { red[wv][0] = m; red[wv][1] = s; }
        __syncthreads();
        if (lin == 0) {
            const double mt = red[0][0] + red[1][0] + red[2][0] + red[3][0];
            const double st = red[0][1] + red[1][1] + red[2][1] + red[3][1];
            out[OUT_LOSS] = (float)(1.25 * st / (256.0 * mt));
        }
    }
}

extern "C" void kernel_launch(void* const* d_in, const int* in_sizes, int n_in,
                              void* d_out, int out_size, void* d_ws, size_t ws_size,
                              hipStream_t stream)
{
    const float* x      = (const float*)d_in[0];   // [16,256,32,32]
    const float* mask   = (const float*)d_in[1];   // [16,1,32,32]
    const float* weight = (const float*)d_in[2];   // [16384,256]
    float* out = (float*)d_out;
    float* ws  = (float*)d_ws;

    float* xt  = ws + OFF_XT;
    signed char* xq8 = (signed char*)(ws + OFF_XQ8);
    signed char* wq8 = (signed char*)(ws + OFF_WHP8);
    float* wn   = ws + OFF_WN;
    float* ns1  = ws + OFF_NS1;
    int*   idx  = (int*)(ws + OFF_IDX);
    unsigned short* candk = (unsigned short*)(ws + OFF_CAND);
    int*   candc = (int*)(ws + OFF_CCNT);
    float* qmaxA = ws + OFF_QMAX;
    float* part = ws + OFF_PART;

    k_prep<<<1024, 256, 0, stream>>>(x, xt, xq8, ns1,
                                     (const float4*)weight, wn, wq8);
    k2_mfma<<<1024, 256, 0, stream>>>(xq8, wq8, candk, candc, qmaxA);
    k3_rescore<<<1024, 256, 0, stream>>>(xt, weight, wn, ns1, qmaxA, candk, candc,
                                         mask, idx, out, part);
    k5_out<<<dim3(32, 8, 16), dim3(32, 8), 0, stream>>>(weight, idx, part, out);
}

// Round 19
// 254.854 us; speedup vs baseline: 1.4227x; 1.4227x over previous
//
#include <hip/hip_runtime.h>

// Problem: B,C,H,W = 16,256,32,32; K=16384. N = 16384 rows.
// R29 (FINAL): R18 post-mortem: A-in-registers regressed (k2 137->239us) --
//      compiler shuffled the invariant A fragments through AGPR copies
//      (VGPR_Count 88 << 160 live) adding VALU to the critical path, and
//      2 blocks/CU halved the TLP covering the B-load chain. Fourth failed
//      k2 structural lever (barrier-free fold R8, K-split-8 R17, forced
//      occupancy R16, A-in-reg R18). Reverting to R15 byte-for-byte: the
//      empirical optimum (254.7us total; k2 137us = i8-MFMA floor ~28us +
//      dependent-chain latency that resisted every lever; tail ~118us within
//      ~20% of compulsory traffic). Ladder: 1203 -> 515 -> 412 -> 372 -> 329
//      -> 295 -> 254.7us (4.7x), output bit-identical throughout.
#define KCODES 16384
#define NPOS   16384
#define KQUART 4096
#define ROWS   64
#define CAPH   80      // per-quarter cap (big headroom at the narrower window)
#define M_INT  3600    // int-space margin = 7.2 x pairwise sigma (~500)
#define SX     21.166666f        // 127/6
#define SW     2080768.0f        // 16384*127

// ws float offsets (within the proven 52.7MB footprint)
#define OFF_XT    0           // [N][256] fp32 packed x
#define OFF_XQ8   4194304     // i8 plane xq [N][256] linear
#define OFF_PART  6291456     // [4096][2] k3 per-wave {mask,err} partials
#define OFF_WHP8  8388608     // i8 plane wq, SWIZZLED [qt][S][w][ct][nn][64B]
#define OFF_CAND  9437184     // u16 [N][4][CAPH=80] candidate codes
#define OFF_WN    12582912    // [K]  |w|^2 (np-pairwise exact)
#define OFF_NS1   12599296    // [N] -|f|^2
#define OFF_IDX   12615680    // [N] final argmax (int)
#define OFF_CCNT  12632064    // int [N][4] candidate counts
#define OFF_QMAX  12697600    // fp32 [N][4] per-quarter int-acc max

#define OUT_LOSS  4194304
#define OUT_IND   4194305

#define AS1 __attribute__((address_space(1)))
#define AS3 __attribute__((address_space(3)))

typedef int  i32x4 __attribute__((ext_vector_type(4)));

// ---------- K_prep: x-path (transpose + xt + xq8 + ns1) / w-path (wn + wq8) ----
__global__ void k_prep(const float* __restrict__ x, float* __restrict__ xt,
                       signed char* __restrict__ xq8, float* __restrict__ ns1,
                       const float4* __restrict__ w4, float* __restrict__ wn,
                       signed char* __restrict__ wq8)
{
    __shared__ __align__(16) float smem[32 * 257];
    __shared__ float t[32][33];
    const int tid = threadIdx.x;

    if (blockIdx.x < 512) {
        const int r0 = blockIdx.x * 32;
        const int b = r0 >> 10, p0 = r0 & 1023;
        const int tx = tid & 31, ty = tid >> 5;      // 32 x 8
#pragma unroll
        for (int ci = 0; ci < 8; ++ci) {
#pragma unroll
            for (int i = 0; i < 4; ++i) {
                const int cl = ty + i * 8;
                t[cl][tx] = x[(b * 256 + ci * 32 + cl) * 1024 + p0 + tx];
            }
            __syncthreads();
#pragma unroll
            for (int i = 0; i < 4; ++i) {
                const int pl = ty + i * 8;
                smem[pl * 257 + ci * 32 + tx] = t[tx][pl];
            }
            __syncthreads();
        }
#pragma unroll
        for (int i = 0; i < 8; ++i) {
            const int row = (tid >> 6) + i * 4, c4 = tid & 63;
            const float* rp = &smem[row * 257 + c4 * 4];
            float4 v;
            v.x = rp[0]; v.y = rp[1]; v.z = rp[2]; v.w = rp[3];
            ((float4*)(xt + (r0 + row) * 256))[c4] = v;
            char4 qv;
            qv.x = (signed char)min(127, max(-127, __float2int_rn(v.x * SX)));
            qv.y = (signed char)min(127, max(-127, __float2int_rn(v.y * SX)));
            qv.z = (signed char)min(127, max(-127, __float2int_rn(v.z * SX)));
            qv.w = (signed char)min(127, max(-127, __float2int_rn(v.w * SX)));
            *(char4*)(xq8 + (r0 + row) * 256 + c4 * 4) = qv;
        }
        __syncthreads();
        const int rl = tid >> 3, j = tid & 7;
        const float* qp = &smem[rl * 257];
        float h[2];
#pragma unroll
        for (int half = 0; half < 2; ++half) {
            const float* p = qp + half * 128;
            float xx = p[j];
            float r = __fmul_rn(xx, xx);
#pragma unroll
            for (int i = 1; i < 16; ++i) {
                float y = p[8 * i + j];
                r = __fadd_rn(r, __fmul_rn(y, y));
            }
            float tt = __fadd_rn(r, __shfl_xor(r, 1));
            tt = __fadd_rn(tt, __shfl_xor(tt, 2));
            tt = __fadd_rn(tt, __shfl_xor(tt, 4));
            h[half] = tt;
        }
        if (j == 0) ns1[r0 + rl] = -__fadd_rn(h[0], h[1]);
    } else {
        float4* rows = (float4*)smem;
        const int r0 = (blockIdx.x - 512) * 32;
#pragma unroll
        for (int i = 0; i < 8; ++i) {
            const int F = r0 * 64 + tid + 256 * i;
            const float4 v = w4[F];
            rows[tid + 256 * i] = v;
            char4 qv;
            qv.x = (signed char)min(127, max(-127, __float2int_rn(v.x * SW)));
            qv.y = (signed char)min(127, max(-127, __float2int_rn(v.y * SW)));
            qv.z = (signed char)min(127, max(-127, __float2int_rn(v.z * SW)));
            qv.w = (signed char)min(127, max(-127, __float2int_rn(v.w * SW)));
            const int row = F >> 6, c4 = F & 63, c = c4 * 4;
            const int qt = row >> 12, kk = row & 4095;
            const int chi = kk >> 8, rem = kk & 255;
            const int wq_ = rem >> 6, ct = (rem >> 4) & 3, n4 = rem & 15;
            const int sidx = qt * 1048576 + (chi * 4 + (c >> 6)) * 16384
                           + wq_ * 4096 + ct * 1024 + n4 * 64 + (c & 63);
            *(char4*)(wq8 + sidx) = qv;
        }
        __syncthreads();
        const int rl = tid >> 3, j = tid & 7;
        const float* qp = (const float*)&rows[rl * 64];
        float h[2];
#pragma unroll
        for (int half = 0; half < 2; ++half) {
            const float* p = qp + half * 128;
            float xx = p[j];
            float r = __fmul_rn(xx, xx);
#pragma unroll
            for (int i = 1; i < 16; ++i) {
                float y = p[8 * i + j];
                r = __fadd_rn(r, __fmul_rn(y, y));
            }
            float tt = __fadd_rn(r, __shfl_xor(r, 1));
            tt = __fadd_rn(tt, __shfl_xor(tt, 2));
            tt = __fadd_rn(tt, __shfl_xor(tt, 4));
            h[half] = tt;
        }
        if (j == 0) wn[r0 + rl] = __fadd_rn(h[0], h[1]);
    }
}

// ---------- K2: 64-row x K-quarter, i8 MFMA (16x16x64), int threshold ----------
// Block = (rowGroup = bid>>2) x (qt = bid&3). 1024 blocks.
__global__ __launch_bounds__(256, 4) void k2_mfma(
    const signed char* __restrict__ xq8, const signed char* __restrict__ wq8,
    unsigned short* __restrict__ candk, int* __restrict__ candc,
    float* __restrict__ qmax)
{
    __shared__ __align__(16) signed char As[16384];   // 16KB: slot16 = g*64 + row
    __shared__ int rowmaxI[ROWS];
    __shared__ int ccnt[ROWS];
    __shared__ unsigned short ck[ROWS][CAPH];         // 10 KB

    const int tid  = threadIdx.x;
    const int lane = tid & 63;
    const int w    = tid >> 6;
    const int q    = lane >> 4;
    const int nn   = lane & 15;
    const int qt   = blockIdx.x & 3;
    const int rowBase = (blockIdx.x >> 2) * ROWS;
    const signed char* wq8Q = wq8 + qt * 1048576;

#pragma unroll
    for (int i = 0; i < 4; ++i) {
        const int slot = i * 256 + tid;
        const int g = slot >> 6, row = slot & 63;
        const signed char* src = xq8 + (rowBase + row) * 256 + g * 16;
        __builtin_amdgcn_global_load_lds((const AS1 void*)src,
                                         (AS3 void*)((char*)&As[0] + slot * 16), 16, 0, 0);
    }
    if (tid < ROWS) { rowmaxI[tid] = (int)0x80000000; ccnt[tid] = 0; }

    const signed char* bptr = wq8Q + (w * 4096 + nn * 64 + q * 16);

    __syncthreads();

    i32x4 b0[4], b1[4];
#pragma unroll
    for (int ct = 0; ct < 4; ++ct)
        b0[ct] = *(const i32x4*)(bptr + ct * 1024);
    const signed char* nps = bptr + 16384;

    for (int ch = 0; ch < 16; ++ch) {
        const int kb = ch * 256;
        i32x4 acc[4][4];
#pragma unroll
        for (int rt = 0; rt < 4; ++rt)
#pragma unroll
            for (int ct = 0; ct < 4; ++ct) acc[rt][ct] = (i32x4){0, 0, 0, 0};

#pragma unroll
        for (int cs2 = 0; cs2 < 2; ++cs2) {
#pragma unroll
            for (int ct = 0; ct < 4; ++ct)
                b1[ct] = *(const i32x4*)(nps + ct * 1024);
            nps += 16384;
#pragma unroll
            for (int rt = 0; rt < 4; ++rt) {
                const int as = ((2 * cs2) * 4 + q) * 64 + rt * 16 + nn;
                const i32x4 ah = *(const i32x4*)&As[as * 16];
#pragma unroll
                for (int ct = 0; ct < 4; ++ct)
                    acc[rt][ct] = __builtin_amdgcn_mfma_i32_16x16x64_i8(ah, b0[ct], acc[rt][ct], 0, 0, 0);
            }
#pragma unroll
            for (int ct = 0; ct < 4; ++ct)
                b0[ct] = *(const i32x4*)(nps + ct * 1024);
            nps += 16384;
#pragma unroll
            for (int rt = 0; rt < 4; ++rt) {
                const int as = ((2 * cs2 + 1) * 4 + q) * 64 + rt * 16 + nn;
                const i32x4 ah = *(const i32x4*)&As[as * 16];
#pragma unroll
                for (int ct = 0; ct < 4; ++ct)
                    acc[rt][ct] = __builtin_amdgcn_mfma_i32_16x16x64_i8(ah, b1[ct], acc[rt][ct], 0, 0, 0);
            }
        }

#pragma unroll
        for (int rt = 0; rt < 4; ++rt)
#pragma unroll
            for (int rg = 0; rg < 4; ++rg) {
                int m = max(max(acc[rt][0][rg], acc[rt][1][rg]),
                            max(acc[rt][2][rg], acc[rt][3][rg]));
                m = max(m, __shfl_xor(m, 1, 64));
                m = max(m, __shfl_xor(m, 2, 64));
                m = max(m, __shfl_xor(m, 4, 64));
                m = max(m, __shfl_xor(m, 8, 64));
                if (nn == 0)
                    atomicMax(&rowmaxI[rt * 16 + q * 4 + rg], m);
            }
        __syncthreads();
#pragma unroll
        for (int rt = 0; rt < 4; ++rt)
#pragma unroll
            for (int rg = 0; rg < 4; ++rg) {
                const int row = rt * 16 + q * 4 + rg;
                const int th = rowmaxI[row] - M_INT;
#pragma unroll
                for (int ct = 0; ct < 4; ++ct)
                    if (acc[rt][ct][rg] >= th) {
                        const int pos = atomicAdd(&ccnt[row], 1);
                        if (pos < CAPH)
                            ck[row][pos] = (unsigned short)(qt * KQUART + kb + w * 64 + ct * 16 + nn);
                    }
            }
        // no trailing barrier: stale rowmax only loosens; M_INT covers the argmax.
    }
    __syncthreads();
    if (tid < ROWS) {
        candc[(rowBase + tid) * 4 + qt] = ccnt[tid];
        qmax[(rowBase + tid) * 4 + qt] = (float)rowmaxI[tid];  // |int| < 2^24: exact
    }
#pragma unroll
    for (int i = 0; i < 20; ++i) {
        const int e = i * 256 + tid;    // 5120 entries = 64 rows x CAPH(80)
        const int row = e / CAPH, pos = e - row * CAPH;
        candk[((rowBase + row) * 4 + qt) * CAPH + pos] = ck[row][pos];
    }
}

// ---------- K3: exact fp32 rescore, quarter-skip, 2-cand ILP, fused loss -------
__global__ __launch_bounds__(256) void k3_rescore(
    const float* __restrict__ xt, const float* __restrict__ weight,
    const float* __restrict__ wn, const float* __restrict__ ns1,
    const float* __restrict__ qmax,
    const unsigned short* __restrict__ candk, const int* __restrict__ candc,
    const float* __restrict__ mask,
    int* __restrict__ idx, float* __restrict__ out, float* __restrict__ part)
{
    const int w = threadIdx.x >> 6, lane = threadIdx.x & 63;
    const int waveId = blockIdx.x * 4 + w;        // 0..4095
    float mm = 0.f, merr = 0.f;
#pragma unroll
    for (int rr = 0; rr < 4; ++rr) {
        const int n = waveId * 4 + rr;
        const float4 xv = ((const float4*)(xt + n * 256))[lane];
        const float nsv = ns1[n];
        const float4 qm = ((const float4*)(qmax + n * 4))[0];
        const float qth = fmaxf(fmaxf(qm.x, qm.y), fmaxf(qm.z, qm.w)) - (float)M_INT;
        float bestd = -3.0e38f; int bestk = 0x7fffffff;
#pragma unroll
        for (int qt = 0; qt < 4; ++qt) {
            const float qv = (qt == 0) ? qm.x : (qt == 1) ? qm.y : (qt == 2) ? qm.z : qm.w;
            if (qv < qth) continue;               // quarter can't hold the argmax
            const int cnt = candc[n * 4 + qt];
            const int base = (n * 4 + qt) * CAPH;
            if (cnt <= CAPH) {
                int i = 0;
                for (; i + 1 < cnt; i += 2) {     // 2-cand ILP; compare order = index order
                    const int ka = candk[base + i], kb = candk[base + i + 1];
                    const float4 wa = ((const float4*)(weight + ka * 256))[lane];
                    const float4 wb = ((const float4*)(weight + kb * 256))[lane];
                    float pa = __fmul_rn(xv.x, wa.x);
                    float pb = __fmul_rn(xv.x, wb.x);
                    pa = __builtin_fmaf(xv.y, wa.y, pa);
                    pb = __builtin_fmaf(xv.y, wb.y, pb);
                    pa = __builtin_fmaf(xv.z, wa.z, pa);
                    pb = __builtin_fmaf(xv.z, wb.z, pb);
                    pa = __builtin_fmaf(xv.w, wa.w, pa);
                    pb = __builtin_fmaf(xv.w, wb.w, pb);
#pragma unroll
                    for (int off = 1; off < 64; off <<= 1) {
                        pa += __shfl_xor(pa, off, 64);
                        pb += __shfl_xor(pb, off, 64);
                    }
                    const float da = __fadd_rn(__fadd_rn(nsv, -wn[ka]), __fmul_rn(2.0f, pa));
                    const float db = __fadd_rn(__fadd_rn(nsv, -wn[kb]), __fmul_rn(2.0f, pb));
                    if (da > bestd || (da == bestd && ka < bestk)) { bestd = da; bestk = ka; }
                    if (db > bestd || (db == bestd && kb < bestk)) { bestd = db; bestk = kb; }
                }
                if (i < cnt) {
                    const int k = candk[base + i];
                    const float4 wv = ((const float4*)(weight + k * 256))[lane];
                    float p = __fmul_rn(xv.x, wv.x);
                    p = __builtin_fmaf(xv.y, wv.y, p);
                    p = __builtin_fmaf(xv.z, wv.z, p);
                    p = __builtin_fmaf(xv.w, wv.w, p);
#pragma unroll
                    for (int off = 1; off < 64; off <<= 1) p += __shfl_xor(p, off, 64);
                    const float dd = __fadd_rn(__fadd_rn(nsv, -wn[k]), __fmul_rn(2.0f, p));
                    if (dd > bestd || (dd == bestd && k < bestk)) { bestd = dd; bestk = k; }
                }
            } else {          // overflow fallback: exact scan of this quarter
                for (int k = qt * KQUART; k < (qt + 1) * KQUART; ++k) {
                    const float4 wv = ((const float4*)(weight + k * 256))[lane];
                    float p = __fmul_rn(xv.x, wv.x);
                    p = __builtin_fmaf(xv.y, wv.y, p);
                    p = __builtin_fmaf(xv.z, wv.z, p);
                    p = __builtin_fmaf(xv.w, wv.w, p);
#pragma unroll
                    for (int off = 1; off < 64; off <<= 1) p += __shfl_xor(p, off, 64);
                    const float dd = __fadd_rn(__fadd_rn(nsv, -wn[k]), __fmul_rn(2.0f, p));
                    if (dd > bestd || (dd == bestd && k < bestk)) { bestd = dd; bestk = k; }
                }
            }
        }
        const int bk = (bestk <= (KCODES - 1)) ? bestk : 0;   // fault guard
        if (lane == 0) { idx[n] = bk; out[OUT_IND + n] = (float)bk; }
        const float4 wv = ((const float4*)(weight + bk * 256))[lane];
        float ex = wv.x - xv.x, ey = wv.y - xv.y, ez = wv.z - xv.z, ew = wv.w - xv.w;
        float s = ex * ex + ey * ey + ez * ez + ew * ew;
#pragma unroll
        for (int off = 1; off < 64; off <<= 1) s += __shfl_xor(s, off, 64);
        const float mval = mask[n];
        mm += mval; merr += mval * s;
    }
    if (lane == 0) { part[waveId * 2 + 0] = mm; part[waveId * 2 + 1] = merr; }
}

// ---------- K5: gather + transpose store; block (0,0,0) also finalizes loss ----
__global__ void k5_out(const float* __restrict__ weight, const int* __restrict__ idx,
                       const float* __restrict__ part, float* __restrict__ out)
{
    __shared__ float t[32][33];
    const int p0 = blockIdx.x * 32, c0 = blockIdx.y * 32, b = blockIdx.z;
    const int tx = threadIdx.x, ty = threadIdx.y;
#pragma unroll
    for (int i = 0; i < 4; ++i) {
        const int pl = ty + i * 8;
        const int n = b * 1024 + p0 + pl;
        t[tx][pl] = weight[idx[n] * 256 + c0 + tx];       // coalesced 128B per row
    }
    __syncthreads();
#pragma unroll
    for (int i = 0; i < 4; ++i) {
        const int cl = ty + i * 8;
        out[(b * 256 + c0 + cl) * 1024 + p0 + tx] = t[cl][tx];   // coalesced in tx
    }
    if (blockIdx.x == 0 && blockIdx.y == 0 && blockIdx.z == 0) {
        __shared__ double red[4][2];
        const int lin = ty * 32 + tx;     // 0..255
        double m = 0.0, s = 0.0;
        for (int i = lin; i < 4096; i += 256) {
            m += (double)part[i * 2 + 0];
            s += (double)part[i * 2 + 1];
        }
        const int lane = lin & 63, wv = lin >> 6;
        for (int o = 32; o > 0; o >>= 1) {
            m += __shfl_down(m, o, 64);
            s += __shfl_down(s, o, 64);
        }
        if (lane == 0) { red[wv][0] = m; red[wv][1] = s; }
        __syncthreads();
        if (lin == 0) {
            const double mt = red[0][0] + red[1][0] + red[2][0] + red[3][0];
            const double st = red[0][1] + red[1][1] + red[2][1] + red[3][1];
            out[OUT_LOSS] = (float)(1.25 * st / (256.0 * mt));
        }
    }
}

extern "C" void kernel_launch(void* const* d_in, const int* in_sizes, int n_in,
                              void* d_out, int out_size, void* d_ws, size_t ws_size,
                              hipStream_t stream)
{
    const float* x      = (const float*)d_in[0];   // [16,256,32,32]
    const float* mask   = (const float*)d_in[1];   // [16,1,32,32]
    const float* weight = (const float*)d_in[2];   // [16384,256]
    float* out = (float*)d_out;
    float* ws  = (float*)d_ws;

    float* xt  = ws + OFF_XT;
    signed char* xq8 = (signed char*)(ws + OFF_XQ8);
    signed char* wq8 = (signed char*)(ws + OFF_WHP8);
    float* wn   = ws + OFF_WN;
    float* ns1  = ws + OFF_NS1;
    int*   idx  = (int*)(ws + OFF_IDX);
    unsigned short* candk = (unsigned short*)(ws + OFF_CAND);
    int*   candc = (int*)(ws + OFF_CCNT);
    float* qmaxA = ws + OFF_QMAX;
    float* part = ws + OFF_PART;

    k_prep<<<1024, 256, 0, stream>>>(x, xt, xq8, ns1,
                                     (const float4*)weight, wn, wq8);
    k2_mfma<<<1024, 256, 0, stream>>>(xq8, wq8, candk, candc, qmaxA);
    k3_rescore<<<1024, 256, 0, stream>>>(xt, weight, wn, ns1, qmaxA, candk, candc,
                                         mask, idx, out, part);
    k5_out<<<dim3(32, 8, 16), dim3(32, 8), 0, stream>>>(weight, idx, part, out);
}